// Round 1
// baseline (262.220 us; speedup 1.0000x reference)
//
#include <hip/hip_runtime.h>

#define F 64
#define F3 192

// ---------------- Kernel 1: per-atom MLP  x = silu(q@W1+b1)@W2+b2 ----------------
// Block = 256 threads = 4 atoms x 64 channels. W2 (48KB) staged in LDS; W1 (16KB)
// read from global (L1-resident). Static LDS kept < 64KB.
__global__ __launch_bounds__(256) void mlp_kernel(
    const float* __restrict__ q, const float* __restrict__ W1,
    const float* __restrict__ b1, const float* __restrict__ W2,
    const float* __restrict__ b2, float* __restrict__ x, int N)
{
    __shared__ float W2s[F * F3];   // 48 KB
    __shared__ float b1s[F];
    __shared__ float b2s[F3];
    __shared__ float qs[4 * F];
    __shared__ float hs[4 * F];

    const int t = threadIdx.x;
    for (int i = t; i < F * F3; i += 256) W2s[i] = W2[i];
    if (t < F)  b1s[t] = b1[t];
    if (t < F3) b2s[t] = b2[t];
    __syncthreads();

    const int a = t >> 6;      // atom within group (0..3)
    const int f = t & 63;      // channel (0..63)
    const int ngroups = (N + 3) >> 2;

    for (int g = blockIdx.x; g < ngroups; g += gridDim.x) {
        const int atom = g * 4 + a;
        qs[t] = (atom < N) ? q[atom * F + f] : 0.f;
        __syncthreads();

        // hidden: h[f] = silu( sum_k q[k] * W1[k][f] + b1[f] )
        float h = b1s[f];
        #pragma unroll
        for (int k = 0; k < F; ++k)
            h = fmaf(qs[a * F + k], W1[k * F + f], h);
        h = h / (1.f + __expf(-h));   // SiLU
        hs[t] = h;
        __syncthreads();

        // out: x[c] = sum_k h[k] * W2[k][c] + b2[c], c = f, f+64, f+128
        float acc0 = b2s[f], acc1 = b2s[F + f], acc2 = b2s[2 * F + f];
        #pragma unroll
        for (int k = 0; k < F; ++k) {
            const float hk = hs[a * F + k];
            acc0 = fmaf(hk, W2s[k * F3 + f],         acc0);
            acc1 = fmaf(hk, W2s[k * F3 + F + f],     acc1);
            acc2 = fmaf(hk, W2s[k * F3 + 2 * F + f], acc2);
        }
        if (atom < N) {
            x[atom * F3 + f]         = acc0;
            x[atom * F3 + F + f]     = acc1;
            x[atom * F3 + 2 * F + f] = acc2;
        }
        __syncthreads();
    }
}

// ---------------- Kernel 2: CSR row starts from sorted idx_i ----------------
__global__ void rowstart_kernel(const int* __restrict__ idx_i,
                                int* __restrict__ row_start, int P, int N)
{
    const int p = blockIdx.x * blockDim.x + threadIdx.x;
    if (p > P) return;
    if (p == P) {
        const int prev = idx_i[P - 1];
        for (int n = prev + 1; n <= N; ++n) row_start[n] = P;
    } else {
        const int cur  = idx_i[p];
        const int prev = (p == 0) ? -1 : idx_i[p - 1];
        for (int n = prev + 1; n <= cur; ++n) row_start[n] = p;
    }
}

// ---------------- Kernel 3: per-atom pair accumulation ----------------
// One block per atom i; thread t owns one output channel:
//   t in [0,64):   dq[f],  f = t
//   t in [64,256): dmu[d][f], d = (t-64)/64, f = (t-64)%64
// No atomics (idx_i sorted -> contiguous pair range per atom). No intra-wave
// divergence (wave0 = dq; waves1-3 = dmu).
__global__ __launch_bounds__(256) void accum_kernel(
    const float* __restrict__ q, const float* __restrict__ mu,
    const float* __restrict__ Wij, const float* __restrict__ dir_ij,
    const int* __restrict__ idx_j, const int* __restrict__ row_start,
    const float* __restrict__ x, float* __restrict__ out, int N)
{
    const int i = blockIdx.x;
    const int t = threadIdx.x;
    const int start = row_start[i];
    const int end   = row_start[i + 1];

    if (t < F) {
        const int f = t;
        float acc = 0.f;
        for (int p = start; p < end; ++p) {
            const int j = idx_j[p];
            acc = fmaf(Wij[(size_t)p * F3 + f], x[(size_t)j * F3 + f], acc);
        }
        out[(size_t)i * F + f] = q[(size_t)i * F + f] + acc;
    } else {
        const int c = t - F;
        const int d = c >> 6;
        const int f = c & 63;
        float acc = 0.f;
        for (int p = start; p < end; ++p) {
            const int j = idx_j[p];
            const float vr = Wij[(size_t)p * F3 + F + f]     * x[(size_t)j * F3 + F + f];
            const float vm = Wij[(size_t)p * F3 + 2 * F + f] * x[(size_t)j * F3 + 2 * F + f];
            acc = fmaf(vr, dir_ij[(size_t)p * 3 + d], acc);
            acc = fmaf(vm, mu[(size_t)j * F3 + d * F + f], acc);
        }
        out[(size_t)N * F + (size_t)i * F3 + c] = mu[(size_t)i * F3 + c] + acc;
    }
}

extern "C" void kernel_launch(void* const* d_in, const int* in_sizes, int n_in,
                              void* d_out, int out_size, void* d_ws, size_t ws_size,
                              hipStream_t stream)
{
    const float* q      = (const float*)d_in[0];
    const float* mu     = (const float*)d_in[1];
    const float* Wij    = (const float*)d_in[2];
    const float* dir_ij = (const float*)d_in[3];
    const int*   idx_i  = (const int*)d_in[4];
    const int*   idx_j  = (const int*)d_in[5];
    // d_in[6] = n_atoms scalar (also derivable from in_sizes)
    const float* W1     = (const float*)d_in[7];
    const float* b1     = (const float*)d_in[8];
    const float* W2     = (const float*)d_in[9];
    const float* b2     = (const float*)d_in[10];

    const int N = in_sizes[0] / F;        // 20000
    const int P = in_sizes[2] / F3;       // 640000

    // workspace layout: x[N*192] floats, then row_start[N+1] ints
    float* x         = (float*)d_ws;
    int*   row_start = (int*)((char*)d_ws + (size_t)N * F3 * sizeof(float));

    float* out = (float*)d_out;

    mlp_kernel<<<1280, 256, 0, stream>>>(q, W1, b1, W2, b2, x, N);
    rowstart_kernel<<<(P + 1 + 255) / 256, 256, 0, stream>>>(idx_i, row_start, P, N);
    accum_kernel<<<N, 256, 0, stream>>>(q, mu, Wij, dir_ij, idx_j, row_start, x, out, N);
}